// Round 15
// baseline (325.319 us; speedup 1.0000x reference)
//
#include <hip/hip_runtime.h>
#include <hip/hip_bf16.h>

// BLAST factorized linear. INSTRUMENTATION ROUND #3:
// k1_T x3 and k2_fused x3 internal reps (idempotent; LDS restage protected by
// rep-boundary barriers) so BOTH kernels exceed the ~76us harness-fill threshold
// and surface in rocprof top-5 with full counters, on the current (R14) code.
// No behavioral changes otherwise.

typedef __bf16 bf16x8 __attribute__((ext_vector_type(8)));
typedef __bf16 bf16x4 __attribute__((ext_vector_type(4)));
typedef float  f32x4  __attribute__((ext_vector_type(4)));

#define IN_DIM  4096
#define OUT_DIM 4096
#define NROWS   8192
#define BJ      16
#define BO      16
#define RANK    128

#define REP_K1  3
#define REP_K2  3

__device__ __forceinline__ bf16x4 cvt4(f32x4 v) {
  bf16x4 r;
  r[0] = (__bf16)v[0]; r[1] = (__bf16)v[1]; r[2] = (__bf16)v[2]; r[3] = (__bf16)v[3];
  return r;
}
__device__ __forceinline__ f32x4 lo4(bf16x8 v) {
  return (f32x4){(float)v[0], (float)v[1], (float)v[2], (float)v[3]};
}
__device__ __forceinline__ f32x4 hi4(bf16x8 v) {
  return (f32x4){(float)v[4], (float)v[5], (float)v[6], (float)v[7]};
}

// ---- prep: frag-order weights, coalesced OUTPUT writes ----
__global__ __launch_bounds__(256) void prep_frag(
    const float* __restrict__ Vt, const float* __restrict__ U,
    __bf16* __restrict__ vtf, __bf16* __restrict__ utf)
{
  const int NV = BJ * 256 * RANK;   // 524288
  int v = blockIdx.x * 256 + threadIdx.x;
  if (v < NV) {
    const int e = v & 7, lane = (v >> 3) & 63, ks = (v >> 9) & 7,
              rf = (v >> 12) & 7, j = v >> 15;
    const int l = lane & 15, lh = lane >> 4;
    const int s = ks * 32 + lh * 8 + e, r = rf * 16 + l;
    vtf[v] = (__bf16)Vt[((size_t)(j * 256 + s)) * RANK + r];
  } else {
    const int u = v - NV;
    const int e = u & 7, lane = (u >> 3) & 63, ks = (u >> 9) & 3,
              pf = (u >> 11) & 15, o = u >> 15;
    const int l = lane & 15, lh = lane >> 4;
    const int r = ks * 32 + lh * 8 + e, p = pf * 16 + l;
    utf[u] = (__bf16)U[((size_t)(o * RANK + r)) * 256 + p];
  }
}

// ---- K1: T-tile GEMM. wg=256 (4 waves), tile 64 rows x 128 r, one j. x REP_K1 ----
__global__ __launch_bounds__(256, 4) void k1_T(
    const float* __restrict__ x, const __bf16* __restrict__ vtf,
    __bf16* __restrict__ T)
{
  __shared__ __bf16 X_lds[64 * 256];   // 32 KB

  const int tid  = threadIdx.x;
  const int lane = tid & 63;
  const int w    = tid >> 6;
  const int l15  = lane & 15;
  const int lhi  = lane >> 4;
  const int b    = blockIdx.x;
  const int j    = (b >> 3) & 15;
  const int mt   = (b & 7) * 16 + (b >> 7);
  const size_t rowbase = (size_t)mt * 64;

  #pragma clang loop unroll(disable)
  for (int rep = 0; rep < REP_K1; ++rep) {
    asm volatile("" ::: "memory");
    if (rep) __syncthreads();    // prior rep's X_lds reads complete before restage

    #pragma unroll
    for (int i = 0; i < 16; ++i) {
      const int row = w * 16 + i;
      const f32x4 v = __builtin_nontemporal_load(
          (const f32x4*)(x + (rowbase + row) * IN_DIM + j * 256 + lane * 4));
      const int c = (lane >> 1) ^ (row & 15);
      *(bf16x4*)&X_lds[row * 256 + c * 8 + (lane & 1) * 4] = cvt4(v);
    }
    __syncthreads();

    f32x4 acc[2][4];
    #pragma unroll
    for (int a = 0; a < 2; ++a)
      #pragma unroll
      for (int c = 0; c < 4; ++c) acc[a][c] = (f32x4){0.f, 0.f, 0.f, 0.f};

    const __bf16* va = vtf + ((size_t)(j * 8 + w * 2) * 8) * 512 + lane * 8;
    #pragma unroll
    for (int ks = 0; ks < 8; ++ks) {
      bf16x8 bfr[4];
      #pragma unroll
      for (int nf = 0; nf < 4; ++nf) {
        const int c = (ks * 4 + lhi) ^ l15;
        bfr[nf] = *(const bf16x8*)&X_lds[(nf * 16 + l15) * 256 + c * 8];
      }
      const bf16x8 a0 = *(const bf16x8*)(va + (size_t)ks * 512);
      const bf16x8 a1 = *(const bf16x8*)(va + (size_t)(8 + ks) * 512);
      #pragma unroll
      for (int nf = 0; nf < 4; ++nf) {
        acc[0][nf] = __builtin_amdgcn_mfma_f32_16x16x32_bf16(a0, bfr[nf], acc[0][nf], 0, 0, 0);
        acc[1][nf] = __builtin_amdgcn_mfma_f32_16x16x32_bf16(a1, bfr[nf], acc[1][nf], 0, 0, 0);
      }
    }
    #pragma unroll
    for (int rfi = 0; rfi < 2; ++rfi)
      #pragma unroll
      for (int nf = 0; nf < 4; ++nf) {
        *(bf16x4*)&T[((size_t)j * NROWS + rowbase + nf * 16 + l15) * RANK
                     + (w * 2 + rfi) * 16 + lhi * 4] = cvt4(acc[rfi][nf]);
      }
  }
}

// ---- K2f: fused fold + out-GEMM. wg=256 (4 waves), 64 rows x one o. x REP_K2 ----
// grid b: o = (b>>3)&15, mt = (b&7)*16 + (b>>7).
__global__ __launch_bounds__(256, 4) void k2_fused(
    const __bf16* __restrict__ T, const float* __restrict__ S,
    const __bf16* __restrict__ utf, const float* __restrict__ bias,
    float* __restrict__ out)
{
  __shared__ float  S_lds[BJ * RANK];    // 8 KB, linear [j][r]
  __shared__ __bf16 u_lds[64 * RANK];    // 16 KB, 16B chunk c -> c ^ (n&15)

  const int tid = threadIdx.x;
  const int b   = blockIdx.x;
  const int o   = (b >> 3) & 15;
  const int mt  = (b & 7) * 16 + (b >> 7);
  const size_t rowbase = (size_t)mt * 64;

  #pragma clang loop unroll(disable)
  for (int rep = 0; rep < REP_K2; ++rep) {
    asm volatile("" ::: "memory");
    if (rep) __syncthreads();    // prior rep's LDS reads complete before restage

    // ---- stage S[o] linear ----
    {
      const float* sb = S + (size_t)o * (BJ * RANK);
      #pragma unroll
      for (int h = 0; h < 2; ++h) {
        const int idx = tid + h * 256;
        *(f32x4*)&S_lds[idx * 4] = *(const f32x4*)(sb + idx * 4);
      }
    }
    __syncthreads();

    // ---- fold: thread = (nb = tid>>4 -> rows nb*4..+4, rs = tid&15 -> r = rs*8..+8) ----
    {
      const int nb = tid >> 4;
      const int rs = tid & 15;
      const __bf16* tg = T + (rowbase + nb * 4) * RANK + rs * 8;
      const size_t jstride = (size_t)NROWS * RANK;
      f32x4 uac[4][2];
      #pragma unroll
      for (int i = 0; i < 4; ++i) {
        uac[i][0] = (f32x4){0.f, 0.f, 0.f, 0.f};
        uac[i][1] = (f32x4){0.f, 0.f, 0.f, 0.f};
      }

      #pragma unroll 4
      for (int jb = 0; jb < BJ; ++jb) {
        const __bf16* tj = tg + (size_t)jb * jstride;
        bf16x8 tv[4];
        #pragma unroll
        for (int i = 0; i < 4; ++i) tv[i] = *(const bf16x8*)(tj + i * RANK);
        const float* sj = &S_lds[jb * RANK + rs * 8];
        const f32x4 s0 = *(const f32x4*)(sj);
        const f32x4 s1 = *(const f32x4*)(sj + 4);
        #pragma unroll
        for (int i = 0; i < 4; ++i) {
          uac[i][0] = s0 * lo4(tv[i]) + uac[i][0];
          uac[i][1] = s1 * hi4(tv[i]) + uac[i][1];
        }
      }
      #pragma unroll
      for (int i = 0; i < 4; ++i) {
        const int n = nb * 4 + i;
        bf16x8 uw;
        const f32x4 a = uac[i][0], bb = uac[i][1];
        uw[0]=(__bf16)a[0];  uw[1]=(__bf16)a[1];  uw[2]=(__bf16)a[2];  uw[3]=(__bf16)a[3];
        uw[4]=(__bf16)bb[0]; uw[5]=(__bf16)bb[1]; uw[6]=(__bf16)bb[2]; uw[7]=(__bf16)bb[3];
        const int swz = rs ^ (n & 15);
        *(bf16x8*)&u_lds[n * RANK + swz * 8] = uw;
      }
    }
    __syncthreads();

    // ---- out GEMM: wave w -> p = [w*64, +64); D=[p,n] -> nt f32x4 stores ----
    {
      const int lane = tid & 63;
      const int w    = tid >> 6;
      const int l15  = lane & 15;
      const int lhi  = lane >> 4;

      f32x4 acc[4][4];
      #pragma unroll
      for (int a = 0; a < 4; ++a)
        #pragma unroll
        for (int c = 0; c < 4; ++c) acc[a][c] = (f32x4){0.f, 0.f, 0.f, 0.f};

      #pragma unroll
      for (int ks = 0; ks < 4; ++ks) {
        bf16x8 ubf[4];
        #pragma unroll
        for (int nf = 0; nf < 4; ++nf) {
          const int swz = (ks * 4 + lhi) ^ l15;
          ubf[nf] = *(const bf16x8*)&u_lds[(nf * 16 + l15) * RANK + swz * 8];
        }
        #pragma unroll
        for (int pi = 0; pi < 4; ++pi) {
          const bf16x8 af = *(const bf16x8*)(
              utf + ((size_t)((o * 16 + w * 4 + pi) * 4 + ks)) * 512 + lane * 8);
          #pragma unroll
          for (int nf = 0; nf < 4; ++nf)
            acc[pi][nf] = __builtin_amdgcn_mfma_f32_16x16x32_bf16(af, ubf[nf], acc[pi][nf], 0, 0, 0);
        }
      }

      #pragma unroll
      for (int pi = 0; pi < 4; ++pi) {
        const int colb = o * 256 + (w * 4 + pi) * 16 + lhi * 4;
        const f32x4 bv = *(const f32x4*)(bias + colb);
        #pragma unroll
        for (int nf = 0; nf < 4; ++nf) {
          __builtin_nontemporal_store(acc[pi][nf] + bv,
              (f32x4*)(out + (rowbase + nf * 16 + l15) * OUT_DIM + colb));
        }
      }
    }
  }
}

extern "C" void kernel_launch(void* const* d_in, const int* in_sizes, int n_in,
                              void* d_out, int out_size, void* d_ws, size_t ws_size,
                              hipStream_t stream) {
  const float* x    = (const float*)d_in[0];
  const float* S    = (const float*)d_in[1];
  const float* U    = (const float*)d_in[2];
  const float* Vt   = (const float*)d_in[3];
  const float* bias = (const float*)d_in[4];
  float* out = (float*)d_out;

  __bf16* vtf = (__bf16*)d_ws;                       // 1 MB
  __bf16* utf = vtf + (size_t)BJ * 8 * 8 * 512;      // 1 MB
  __bf16* T   = utf + (size_t)BO * 16 * 4 * 512;     // 32 MB: T[16][8192][128]

  prep_frag<<<(2 * 524288) / 256, 256, 0, stream>>>(Vt, U, vtf, utf);
  k1_T<<<(NROWS / 64) * BJ, 256, 0, stream>>>(x, vtf, T);
  k2_fused<<<(NROWS / 64) * BO, 256, 0, stream>>>(T, S, utf, bias, out);
}

// Round 16
// 180.984 us; speedup vs baseline: 1.7975x; 1.7975x over previous
//
#include <hip/hip_runtime.h>
#include <hip/hip_bf16.h>

// BLAST factorized linear, 3 kernels:
//   prep: frag-order weights vtf/utf (coalesced writes)
//   K1  : T[j][n][r] = sum_s X[n,j*256+s]*Vt[j,s,r]  (GEMM, X via LDS, nt X loads)
//   K2f : one wg per 16-row strip, ALL 16 o's per wg:
//         T strip -> 16 bf16x8 REGS per thread (read once; kills the 16x o-grid
//         re-read of T through L2 that R15 counters exposed);
//         per o: fold (S via L2 broadcast) -> u dbuf LDS (1 barrier) -> GEMM
//         (frag-order utf) -> plain f32x4 stores.

typedef __bf16 bf16x8 __attribute__((ext_vector_type(8)));
typedef __bf16 bf16x4 __attribute__((ext_vector_type(4)));
typedef float  f32x4  __attribute__((ext_vector_type(4)));

#define IN_DIM  4096
#define OUT_DIM 4096
#define NROWS   8192
#define BJ      16
#define BO      16
#define RANK    128

__device__ __forceinline__ bf16x4 cvt4(f32x4 v) {
  bf16x4 r;
  r[0] = (__bf16)v[0]; r[1] = (__bf16)v[1]; r[2] = (__bf16)v[2]; r[3] = (__bf16)v[3];
  return r;
}
__device__ __forceinline__ f32x4 lo4(bf16x8 v) {
  return (f32x4){(float)v[0], (float)v[1], (float)v[2], (float)v[3]};
}
__device__ __forceinline__ f32x4 hi4(bf16x8 v) {
  return (f32x4){(float)v[4], (float)v[5], (float)v[6], (float)v[7]};
}

// ---- prep: frag-order weights, coalesced OUTPUT writes ----
__global__ __launch_bounds__(256) void prep_frag(
    const float* __restrict__ Vt, const float* __restrict__ U,
    __bf16* __restrict__ vtf, __bf16* __restrict__ utf)
{
  const int NV = BJ * 256 * RANK;   // 524288
  int v = blockIdx.x * 256 + threadIdx.x;
  if (v < NV) {
    const int e = v & 7, lane = (v >> 3) & 63, ks = (v >> 9) & 7,
              rf = (v >> 12) & 7, j = v >> 15;
    const int l = lane & 15, lh = lane >> 4;
    const int s = ks * 32 + lh * 8 + e, r = rf * 16 + l;
    vtf[v] = (__bf16)Vt[((size_t)(j * 256 + s)) * RANK + r];
  } else {
    const int u = v - NV;
    const int e = u & 7, lane = (u >> 3) & 63, ks = (u >> 9) & 3,
              pf = (u >> 11) & 15, o = u >> 15;
    const int l = lane & 15, lh = lane >> 4;
    const int r = ks * 32 + lh * 8 + e, p = pf * 16 + l;
    utf[u] = (__bf16)U[((size_t)(o * RANK + r)) * 256 + p];
  }
}

// ---- K1: T-tile GEMM. wg=256 (4 waves), tile 64 rows x 128 r, one j. ----
// T stored j-major: T[j][n][128].
__global__ __launch_bounds__(256, 4) void k1_T(
    const float* __restrict__ x, const __bf16* __restrict__ vtf,
    __bf16* __restrict__ T)
{
  __shared__ __bf16 X_lds[64 * 256];   // 32 KB

  const int tid  = threadIdx.x;
  const int lane = tid & 63;
  const int w    = tid >> 6;
  const int l15  = lane & 15;
  const int lhi  = lane >> 4;
  const int b    = blockIdx.x;
  const int j    = (b >> 3) & 15;
  const int mt   = (b & 7) * 16 + (b >> 7);
  const size_t rowbase = (size_t)mt * 64;

  #pragma unroll
  for (int i = 0; i < 16; ++i) {
    const int row = w * 16 + i;
    const f32x4 v = __builtin_nontemporal_load(
        (const f32x4*)(x + (rowbase + row) * IN_DIM + j * 256 + lane * 4));
    const int c = (lane >> 1) ^ (row & 15);
    *(bf16x4*)&X_lds[row * 256 + c * 8 + (lane & 1) * 4] = cvt4(v);
  }
  __syncthreads();

  f32x4 acc[2][4];
  #pragma unroll
  for (int a = 0; a < 2; ++a)
    #pragma unroll
    for (int c = 0; c < 4; ++c) acc[a][c] = (f32x4){0.f, 0.f, 0.f, 0.f};

  const __bf16* va = vtf + ((size_t)(j * 8 + w * 2) * 8) * 512 + lane * 8;
  #pragma unroll
  for (int ks = 0; ks < 8; ++ks) {
    bf16x8 bfr[4];
    #pragma unroll
    for (int nf = 0; nf < 4; ++nf) {
      const int c = (ks * 4 + lhi) ^ l15;
      bfr[nf] = *(const bf16x8*)&X_lds[(nf * 16 + l15) * 256 + c * 8];
    }
    const bf16x8 a0 = *(const bf16x8*)(va + (size_t)ks * 512);
    const bf16x8 a1 = *(const bf16x8*)(va + (size_t)(8 + ks) * 512);
    #pragma unroll
    for (int nf = 0; nf < 4; ++nf) {
      acc[0][nf] = __builtin_amdgcn_mfma_f32_16x16x32_bf16(a0, bfr[nf], acc[0][nf], 0, 0, 0);
      acc[1][nf] = __builtin_amdgcn_mfma_f32_16x16x32_bf16(a1, bfr[nf], acc[1][nf], 0, 0, 0);
    }
  }
  #pragma unroll
  for (int rfi = 0; rfi < 2; ++rfi)
    #pragma unroll
    for (int nf = 0; nf < 4; ++nf) {
      *(bf16x4*)&T[((size_t)j * NROWS + rowbase + nf * 16 + l15) * RANK
                   + (w * 2 + rfi) * 16 + lhi * 4] = cvt4(acc[rfi][nf]);
    }
}

// ---- K2f: one wg per 16-row strip; T in regs; all 16 o's in-wg. ----
__global__ __launch_bounds__(256, 3) void k2_fused(
    const __bf16* __restrict__ T, const float* __restrict__ S,
    const __bf16* __restrict__ utf, const float* __restrict__ bias,
    float* __restrict__ out)
{
  __shared__ __bf16 u_lds[2][16 * RANK];   // 2 x 4 KB, chunk c -> c ^ n

  const int tid  = threadIdx.x;
  const int lane = tid & 63;
  const int w    = tid >> 6;
  const int l15  = lane & 15;
  const int lhi  = lane >> 4;
  const size_t rowbase = (size_t)blockIdx.x * 16;

  // fold mapping: n = tid&15 row, rs = tid>>4 -> r = rs*8..+8
  const int n  = tid & 15;
  const int rs = tid >> 4;

  // ---- load T strip into regs, read-once: tr[j] = T[j][rowbase+n][rs*8..+8] ----
  bf16x8 tr[BJ];
  {
    const __bf16* tg = T + (rowbase + n) * RANK + rs * 8;
    const size_t jstride = (size_t)NROWS * RANK;
    #pragma unroll
    for (int j = 0; j < BJ; ++j) tr[j] = *(const bf16x8*)(tg + (size_t)j * jstride);
  }

  // ---- o-loop: fold (reg T, L2-broadcast S) -> u dbuf -> GEMM ----
  for (int o = 0; o < BO; ++o) {
    {
      f32x4 u0 = {0.f, 0.f, 0.f, 0.f}, u1 = {0.f, 0.f, 0.f, 0.f};
      const float* sp = S + ((size_t)o * BJ) * RANK + rs * 8;
      #pragma unroll 4
      for (int j = 0; j < BJ; ++j) {
        const f32x4 s0 = *(const f32x4*)(sp + j * RANK);
        const f32x4 s1 = *(const f32x4*)(sp + j * RANK + 4);
        u0 = s0 * lo4(tr[j]) + u0;
        u1 = s1 * hi4(tr[j]) + u1;
      }
      bf16x8 uw;
      uw[0]=(__bf16)u0[0]; uw[1]=(__bf16)u0[1]; uw[2]=(__bf16)u0[2]; uw[3]=(__bf16)u0[3];
      uw[4]=(__bf16)u1[0]; uw[5]=(__bf16)u1[1]; uw[6]=(__bf16)u1[2]; uw[7]=(__bf16)u1[3];
      *(bf16x8*)&u_lds[o & 1][n * RANK + (rs ^ n) * 8] = uw;
    }
    __syncthreads();
    // GEMM: 16 rows x 256 cols (one o); wave w -> p = [w*64, +64); D=[p,n]
    {
      bf16x8 ubf[4];
      #pragma unroll
      for (int ks = 0; ks < 4; ++ks) {
        const int swz = (ks * 4 + lhi) ^ l15;
        ubf[ks] = *(const bf16x8*)&u_lds[o & 1][l15 * RANK + swz * 8];
      }
      f32x4 acc[4];
      #pragma unroll
      for (int pi = 0; pi < 4; ++pi) acc[pi] = (f32x4){0.f, 0.f, 0.f, 0.f};
      #pragma unroll
      for (int pi = 0; pi < 4; ++pi) {
        #pragma unroll
        for (int ks = 0; ks < 4; ++ks) {
          const bf16x8 af = *(const bf16x8*)(
              utf + ((size_t)((o * 16 + w * 4 + pi) * 4 + ks)) * 512 + lane * 8);
          acc[pi] = __builtin_amdgcn_mfma_f32_16x16x32_bf16(af, ubf[ks], acc[pi], 0, 0, 0);
        }
      }
      float* orow = out + (rowbase + l15) * OUT_DIM + o * 256;
      #pragma unroll
      for (int pi = 0; pi < 4; ++pi) {
        const int cb = (w * 4 + pi) * 16 + lhi * 4;
        const f32x4 bv = *(const f32x4*)(bias + o * 256 + cb);
        *(f32x4*)(orow + cb) = acc[pi] + bv;
      }
    }
    // dbuf: fold(o+1) writes the other buffer; buffer o&1 next written at
    // fold(o+2), which is after barrier(o+1) -> no trailing barrier needed.
  }
}

extern "C" void kernel_launch(void* const* d_in, const int* in_sizes, int n_in,
                              void* d_out, int out_size, void* d_ws, size_t ws_size,
                              hipStream_t stream) {
  const float* x    = (const float*)d_in[0];
  const float* S    = (const float*)d_in[1];
  const float* U    = (const float*)d_in[2];
  const float* Vt   = (const float*)d_in[3];
  const float* bias = (const float*)d_in[4];
  float* out = (float*)d_out;

  __bf16* vtf = (__bf16*)d_ws;                       // 1 MB
  __bf16* utf = vtf + (size_t)BJ * 8 * 8 * 512;      // 1 MB
  __bf16* T   = utf + (size_t)BO * 16 * 4 * 512;     // 32 MB: T[16][8192][128]

  prep_frag<<<(2 * 524288) / 256, 256, 0, stream>>>(Vt, U, vtf, utf);
  k1_T<<<(NROWS / 64) * BJ, 256, 0, stream>>>(x, vtf, T);
  k2_fused<<<NROWS / 16, 256, 0, stream>>>(T, S, utf, bias, out);
}

// Round 17
// 103.653 us; speedup vs baseline: 3.1386x; 1.7461x over previous
//
#include <hip/hip_runtime.h>
#include <hip/hip_bf16.h>

// BLAST factorized linear, 3 kernels:
//   prep: frag-order weights vtf/utf via LDS transpose (coalesced R+W)
//   K1  : T[j][n][r] = sum_s X[n,j*256+s]*Vt[j,s,r]  (GEMM, X via LDS)
//   K2f : per (64-row tile, o): fold u in regs -- T full-sector loads, S read
//         DIRECTLY from L2 (contiguous 512B broadcast segments; no S_lds, no
//         stage phase) -> u XOR-swizzled LDS (16 KB -> 8 wg/CU) -> 1 barrier ->
//         out = bias + u @ U_o (MFMA, frag-order utf, nt f32x4 stores).

typedef __bf16 bf16x8 __attribute__((ext_vector_type(8)));
typedef __bf16 bf16x4 __attribute__((ext_vector_type(4)));
typedef float  f32x4  __attribute__((ext_vector_type(4)));

#define IN_DIM  4096
#define OUT_DIM 4096
#define NROWS   8192
#define BJ      16
#define BO      16
#define RANK    128

__device__ __forceinline__ bf16x4 cvt4(f32x4 v) {
  bf16x4 r;
  r[0] = (__bf16)v[0]; r[1] = (__bf16)v[1]; r[2] = (__bf16)v[2]; r[3] = (__bf16)v[3];
  return r;
}
__device__ __forceinline__ f32x4 lo4(bf16x8 v) {
  return (f32x4){(float)v[0], (float)v[1], (float)v[2], (float)v[3]};
}
__device__ __forceinline__ f32x4 hi4(bf16x8 v) {
  return (f32x4){(float)v[4], (float)v[5], (float)v[6], (float)v[7]};
}

// ---- prep A: vtf via LDS transpose. One block per (j, ks): 128 blocks. ----
// vtf[(((j*8+rf)*8+ks)*64 + lh*16+l)*8 + e] = Vt[j][ks*32 + lh*8+e][rf*16 + l]
__global__ __launch_bounds__(256) void prep_vtf(
    const float* __restrict__ Vt, __bf16* __restrict__ vtf)
{
  __shared__ float t[32 * 129];          // 32 s-rows x 128 r (+1 pad)
  const int tid = threadIdx.x;
  const int j   = blockIdx.x >> 3;
  const int ks  = blockIdx.x & 7;

  // coalesced read: Vt[j][ks*32 + sr][r4*4 ..+4]
  #pragma unroll
  for (int it = 0; it < 4; ++it) {
    const int c  = tid + it * 256;       // 0..1023
    const int sr = c >> 5, r4 = c & 31;
    const f32x4 v = *(const f32x4*)(Vt + ((size_t)(j * 256 + ks * 32 + sr)) * RANK + r4 * 4);
    t[sr * 129 + r4 * 4 + 0] = v[0];
    t[sr * 129 + r4 * 4 + 1] = v[1];
    t[sr * 129 + r4 * 4 + 2] = v[2];
    t[sr * 129 + r4 * 4 + 3] = v[3];
  }
  __syncthreads();

  // coalesced write: 2 rf's per thread-quarter
  const int lane = tid & 63;
  const int l = lane & 15, lh = lane >> 4;
  #pragma unroll
  for (int h = 0; h < 2; ++h) {
    const int rf = (tid >> 6) + h * 4;   // 0..7
    bf16x8 o8;
    #pragma unroll
    for (int e = 0; e < 8; ++e)
      o8[e] = (__bf16)t[(lh * 8 + e) * 129 + rf * 16 + l];
    *(bf16x8*)&vtf[(((size_t)(j * 8 + rf) * 8 + ks) * 64 + lane) * 8] = o8;
  }
}

// ---- prep B: utf via LDS transpose. One block per (o, ks): 64 blocks. ----
// utf[(((o*16+pf)*4+ks)*64 + lh*16+l)*8 + e] = U[o][ks*32 + lh*8+e][pf*16 + l]
__global__ __launch_bounds__(256) void prep_utf(
    const float* __restrict__ U, __bf16* __restrict__ utf)
{
  __shared__ float t[32 * 257];          // 32 r-rows x 256 p (+1 pad)
  const int tid = threadIdx.x;
  const int o   = blockIdx.x >> 2;
  const int ks  = blockIdx.x & 3;

  #pragma unroll
  for (int it = 0; it < 8; ++it) {
    const int c  = tid + it * 256;       // 0..2047
    const int rr = c >> 6, p4 = c & 63;
    const f32x4 v = *(const f32x4*)(U + ((size_t)(o * RANK + ks * 32 + rr)) * 256 + p4 * 4);
    t[rr * 257 + p4 * 4 + 0] = v[0];
    t[rr * 257 + p4 * 4 + 1] = v[1];
    t[rr * 257 + p4 * 4 + 2] = v[2];
    t[rr * 257 + p4 * 4 + 3] = v[3];
  }
  __syncthreads();

  const int lane = tid & 63;
  const int l = lane & 15, lh = lane >> 4;
  #pragma unroll
  for (int h = 0; h < 4; ++h) {
    const int pf = (tid >> 6) + h * 4;   // 0..15
    bf16x8 o8;
    #pragma unroll
    for (int e = 0; e < 8; ++e)
      o8[e] = (__bf16)t[(lh * 8 + e) * 257 + pf * 16 + l];
    *(bf16x8*)&utf[(((size_t)(o * 16 + pf) * 4 + ks) * 64 + lane) * 8] = o8;
  }
}

// ---- K1: T-tile GEMM. wg=256 (4 waves), tile 64 rows x 128 r, one j. ----
// T stored j-major: T[j][n][128].
__global__ __launch_bounds__(256, 4) void k1_T(
    const float* __restrict__ x, const __bf16* __restrict__ vtf,
    __bf16* __restrict__ T)
{
  __shared__ __bf16 X_lds[64 * 256];   // 32 KB

  const int tid  = threadIdx.x;
  const int lane = tid & 63;
  const int w    = tid >> 6;
  const int l15  = lane & 15;
  const int lhi  = lane >> 4;
  const int b    = blockIdx.x;
  const int j    = (b >> 3) & 15;
  const int mt   = (b & 7) * 16 + (b >> 7);
  const size_t rowbase = (size_t)mt * 64;

  #pragma unroll
  for (int i = 0; i < 16; ++i) {
    const int row = w * 16 + i;
    const f32x4 v = __builtin_nontemporal_load(
        (const f32x4*)(x + (rowbase + row) * IN_DIM + j * 256 + lane * 4));
    const int c = (lane >> 1) ^ (row & 15);
    *(bf16x4*)&X_lds[row * 256 + c * 8 + (lane & 1) * 4] = cvt4(v);
  }
  __syncthreads();

  f32x4 acc[2][4];
  #pragma unroll
  for (int a = 0; a < 2; ++a)
    #pragma unroll
    for (int c = 0; c < 4; ++c) acc[a][c] = (f32x4){0.f, 0.f, 0.f, 0.f};

  const __bf16* va = vtf + ((size_t)(j * 8 + w * 2) * 8) * 512 + lane * 8;
  #pragma unroll
  for (int ks = 0; ks < 8; ++ks) {
    bf16x8 bfr[4];
    #pragma unroll
    for (int nf = 0; nf < 4; ++nf) {
      const int c = (ks * 4 + lhi) ^ l15;
      bfr[nf] = *(const bf16x8*)&X_lds[(nf * 16 + l15) * 256 + c * 8];
    }
    const bf16x8 a0 = *(const bf16x8*)(va + (size_t)ks * 512);
    const bf16x8 a1 = *(const bf16x8*)(va + (size_t)(8 + ks) * 512);
    #pragma unroll
    for (int nf = 0; nf < 4; ++nf) {
      acc[0][nf] = __builtin_amdgcn_mfma_f32_16x16x32_bf16(a0, bfr[nf], acc[0][nf], 0, 0, 0);
      acc[1][nf] = __builtin_amdgcn_mfma_f32_16x16x32_bf16(a1, bfr[nf], acc[1][nf], 0, 0, 0);
    }
  }
  #pragma unroll
  for (int rfi = 0; rfi < 2; ++rfi)
    #pragma unroll
    for (int nf = 0; nf < 4; ++nf) {
      *(bf16x4*)&T[((size_t)j * NROWS + rowbase + nf * 16 + l15) * RANK
                   + (w * 2 + rfi) * 16 + lhi * 4] = cvt4(acc[rfi][nf]);
    }
}

// ---- K2f: fused fold + out-GEMM. wg=256 (4 waves), 64 rows x one o. ----
// grid b: o = (b>>3)&15, mt = (b&7)*16 + (b>>7). ONE barrier; 16 KB LDS.
__global__ __launch_bounds__(256, 4) void k2_fused(
    const __bf16* __restrict__ T, const float* __restrict__ S,
    const __bf16* __restrict__ utf, const float* __restrict__ bias,
    float* __restrict__ out)
{
  __shared__ __bf16 u_lds[64 * RANK];    // 16 KB, 16B chunk c -> c ^ (n&15)

  const int tid = threadIdx.x;
  const int b   = blockIdx.x;
  const int o   = (b >> 3) & 15;
  const int mt  = (b & 7) * 16 + (b >> 7);
  const size_t rowbase = (size_t)mt * 64;

  // ---- fold in regs: thread = (nb = tid>>4 -> rows nb*4..+4, rs = tid&15) ----
  // T loads: 4 segments x 256 B per instr. S loads: 16 lanes span contiguous
  // 512 B (L2-broadcast, S is 128 KB / L2-resident) -- no S staging phase.
  {
    const int nb = tid >> 4;          // 0..15
    const int rs = tid & 15;          // 0..15
    const __bf16* tg = T + (rowbase + nb * 4) * RANK + rs * 8;
    const float*  sp = S + (size_t)o * (BJ * RANK) + rs * 8;
    const size_t jstride = (size_t)NROWS * RANK;
    f32x4 uac[4][2];
    #pragma unroll
    for (int i = 0; i < 4; ++i) {
      uac[i][0] = (f32x4){0.f, 0.f, 0.f, 0.f};
      uac[i][1] = (f32x4){0.f, 0.f, 0.f, 0.f};
    }

    #pragma unroll 4
    for (int jb = 0; jb < BJ; ++jb) {
      const __bf16* tj = tg + (size_t)jb * jstride;
      bf16x8 tv[4];
      #pragma unroll
      for (int i = 0; i < 4; ++i) tv[i] = *(const bf16x8*)(tj + i * RANK);
      const f32x4 s0 = *(const f32x4*)(sp + jb * RANK);
      const f32x4 s1 = *(const f32x4*)(sp + jb * RANK + 4);
      #pragma unroll
      for (int i = 0; i < 4; ++i) {
        uac[i][0] = s0 * lo4(tv[i]) + uac[i][0];
        uac[i][1] = s1 * hi4(tv[i]) + uac[i][1];
      }
    }
    #pragma unroll
    for (int i = 0; i < 4; ++i) {
      const int n = nb * 4 + i;
      bf16x8 uw;
      const f32x4 a = uac[i][0], bb = uac[i][1];
      uw[0]=(__bf16)a[0];  uw[1]=(__bf16)a[1];  uw[2]=(__bf16)a[2];  uw[3]=(__bf16)a[3];
      uw[4]=(__bf16)bb[0]; uw[5]=(__bf16)bb[1]; uw[6]=(__bf16)bb[2]; uw[7]=(__bf16)bb[3];
      const int swz = rs ^ (n & 15);
      *(bf16x8*)&u_lds[n * RANK + swz * 8] = uw;
    }
  }
  __syncthreads();

  // ---- out GEMM: wave w -> p = [w*64, +64); D=[p,n] -> nt f32x4 stores ----
  {
    const int lane = tid & 63;
    const int w    = tid >> 6;
    const int l15  = lane & 15;
    const int lhi  = lane >> 4;

    f32x4 acc[4][4];
    #pragma unroll
    for (int a = 0; a < 4; ++a)
      #pragma unroll
      for (int c = 0; c < 4; ++c) acc[a][c] = (f32x4){0.f, 0.f, 0.f, 0.f};

    #pragma unroll
    for (int ks = 0; ks < 4; ++ks) {
      bf16x8 ubf[4];
      #pragma unroll
      for (int nf = 0; nf < 4; ++nf) {
        const int swz = (ks * 4 + lhi) ^ l15;
        ubf[nf] = *(const bf16x8*)&u_lds[(nf * 16 + l15) * RANK + swz * 8];
      }
      #pragma unroll
      for (int pi = 0; pi < 4; ++pi) {
        const bf16x8 af = *(const bf16x8*)(
            utf + ((size_t)((o * 16 + w * 4 + pi) * 4 + ks)) * 512 + lane * 8);
        #pragma unroll
        for (int nf = 0; nf < 4; ++nf)
          acc[pi][nf] = __builtin_amdgcn_mfma_f32_16x16x32_bf16(af, ubf[nf], acc[pi][nf], 0, 0, 0);
      }
    }

    #pragma unroll
    for (int pi = 0; pi < 4; ++pi) {
      const int colb = o * 256 + (w * 4 + pi) * 16 + lhi * 4;
      const f32x4 bv = *(const f32x4*)(bias + colb);
      #pragma unroll
      for (int nf = 0; nf < 4; ++nf) {
        __builtin_nontemporal_store(acc[pi][nf] + bv,
            (f32x4*)(out + (rowbase + nf * 16 + l15) * OUT_DIM + colb));
      }
    }
  }
}

extern "C" void kernel_launch(void* const* d_in, const int* in_sizes, int n_in,
                              void* d_out, int out_size, void* d_ws, size_t ws_size,
                              hipStream_t stream) {
  const float* x    = (const float*)d_in[0];
  const float* S    = (const float*)d_in[1];
  const float* U    = (const float*)d_in[2];
  const float* Vt   = (const float*)d_in[3];
  const float* bias = (const float*)d_in[4];
  float* out = (float*)d_out;

  __bf16* vtf = (__bf16*)d_ws;                       // 1 MB
  __bf16* utf = vtf + (size_t)BJ * 8 * 8 * 512;      // 1 MB
  __bf16* T   = utf + (size_t)BO * 16 * 4 * 512;     // 32 MB: T[16][8192][128]

  prep_vtf<<<BJ * 8, 256, 0, stream>>>(Vt, vtf);
  prep_utf<<<BO * 4, 256, 0, stream>>>(U, utf);
  k1_T<<<(NROWS / 64) * BJ, 256, 0, stream>>>(x, vtf, T);
  k2_fused<<<(NROWS / 64) * BO, 256, 0, stream>>>(T, S, utf, bias, out);
}